// Round 12
// baseline (30760.040 us; speedup 1.0000x reference)
//
#include <hip/hip_runtime.h>
#include <stdint.h>

// Problem dims
#define T_STEPS 8192
#define DIN     2048
#define HD      2048
#define G3      6144
#define EOUT    512

// Scan partition: 64 A-blocks own 32 r-cols; 64 B-blocks own 32 z-cols +
// 32 a-cols + the h-update (z computed locally on B, off the critical path).
#define NA 64
#define NB 64
#define HP 1024          // h/rh broadcast: 1024 u64 pairs {tag | bf16 hi | bf16 lo}
#define NREP 8           // broadcast replicas == waves/block (wave w stores replica w)
#define SPIN_MAX (1<<20)

typedef unsigned long long u64;
typedef __attribute__((ext_vector_type(8))) __bf16 bf16x8;
typedef __attribute__((ext_vector_type(8))) unsigned short u16x8;
typedef __attribute__((ext_vector_type(4))) float f32x4;

__device__ __forceinline__ uint16_t f2bf(float v){   // RNE f32->bf16
  uint32_t x = __float_as_uint(v);
  return (uint16_t)((x + 0x7fffu + ((x >> 16) & 1u)) >> 16);
}

__device__ __forceinline__ u64 aload(const u64* p){
  return __hip_atomic_load(p, __ATOMIC_RELAXED, __HIP_MEMORY_SCOPE_AGENT);
}
__device__ __forceinline__ void astore(u64* p, u64 v){
  __hip_atomic_store(p, v, __ATOMIC_RELAXED, __HIP_MEMORY_SCOPE_AGENT);
}

// A-fragment loader: lane supplies A[m = lane&15][k = kb + j], j=0..7,
// from w_h column `col` (f32, row-major, stride G3), converted to bf16.
__device__ __forceinline__ bf16x8 load_afrag(const float* __restrict__ w, int col, int kb){
  u16x8 r;
  #pragma unroll
  for (int j = 0; j < 8; ++j)
    r[j] = f2bf(w[(size_t)(kb + j)*G3 + col]);
  return __builtin_bit_cast(bf16x8, r);
}

// Wave-local tagged slice poll + LDS deposit — SOFTWARE-PIPELINED: the next
// round's loads are issued before the current round's tags are tested, so the
// retry period ~ RTT/2 instead of a full dependent round trip. If OWN, lanes
// 0..15 additionally poll own_p[lane] (the block's own h u64s) and return it.
template<bool OWN>
__device__ __forceinline__ u64 poll_slice(const u64* slice, const u64* own_p,
                                          uint32_t want, uint32_t* lds_slice,
                                          int lane, volatile int* deadp){
  const u64* p0 = slice + 2*lane;
  const u64* p1 = p0 + 1;
  const bool need_own = OWN && (lane < 16);
  u64 a0 = aload(p0), a1 = aload(p1);
  u64 ao = need_own ? aload(own_p) : 0;
  int spins = 0;
  for(;;){
    u64 b0 = aload(p0), b1 = aload(p1);          // next batch already in flight
    u64 bo = need_own ? aload(own_p) : 0;
    bool ok = (uint32_t)(a0 >> 32) >= want &&
              (uint32_t)(a1 >> 32) >= want &&
              (!need_own || (uint32_t)(ao >> 32) >= want);
    if (__all(ok)) break;
    a0 = b0; a1 = b1; ao = bo;
    ++spins;
    if ((spins & 3) == 0) __builtin_amdgcn_s_sleep(1);
    if ((spins & 255) == 0){
      if (*deadp) break;
      if (spins > SPIN_MAX){ *deadp = 1; break; }
    }
  }
  *(u64*)&lds_slice[2*lane] = ((u64)(uint32_t)a1 << 32) | (u64)(uint32_t)a0;
  return ao;
}

// One matvec pass over this wave's 256-elem k-slice: 16 MFMAs, two 16-col
// chains (wA, wB). Partials -> red[col*9 + wid]. Reads only the wave's own
// LDS slice (no cross-wave dependency -> no barrier needed before this).
__device__ __forceinline__ void mv_pass(const uint32_t* vp,
                                        const bf16x8* wA, const bf16x8* wB,
                                        float* red, int wid, int lane){
  const int boff = (lane >> 4) << 2;
  f32x4 acc0 = {0.f,0.f,0.f,0.f}, acc1 = {0.f,0.f,0.f,0.f};
  #pragma unroll
  for (int s = 0; s < 8; ++s){
    uint4 bu = *(const uint4*)(vp + s*16 + boff);
    bf16x8 bf = __builtin_bit_cast(bf16x8, bu);
    acc0 = __builtin_amdgcn_mfma_f32_16x16x32_bf16(wA[s], bf, acc0, 0, 0, 0);
    acc1 = __builtin_amdgcn_mfma_f32_16x16x32_bf16(wB[s], bf, acc1, 0, 0, 0);
  }
  if ((lane & 15) == 0){                  // D[:,0]: m = (lane>>4)*4 + r
    int mb = (lane >> 4) << 2;
    #pragma unroll
    for (int r = 0; r < 4; ++r){
      red[(mb + r)*9 + wid]      = acc0[r];
      red[(16 + mb + r)*9 + wid] = acc1[r];
    }
  }
}

// ------- gates GEMM (MFMA bf16): C[T,6144] = X[T,2048] @ Wi[2048,6144] -----
__global__ __launch_bounds__(512) void gates_gemm(const float* __restrict__ A,
                                                  const float* __restrict__ B,
                                                  float* __restrict__ C){
  __shared__ uint16_t Asb[128*40];
  __shared__ uint16_t Bsb[128*40];
  const int bm = blockIdx.x / (G3/128);
  const int bn = blockIdx.x % (G3/128);
  const int row0 = bm*128, col0 = bn*128;
  const int tid  = threadIdx.x;
  const int lane = tid & 63, wid = tid >> 6;
  const int wr = wid >> 2, wc = wid & 3;         // wave grid 2x4
  f32x4 acc[4][2] = {};
  for (int k0 = 0; k0 < DIN; k0 += 32){
    {   // stage A: [m][k] bf16
      int m = tid >> 2, ks = (tid & 3) * 8;
      const float* src = A + (size_t)(row0 + m)*DIN + k0 + ks;
      float4 f0 = *(const float4*)src;
      float4 f1 = *(const float4*)(src + 4);
      u16x8 pk;
      pk[0]=f2bf(f0.x); pk[1]=f2bf(f0.y); pk[2]=f2bf(f0.z); pk[3]=f2bf(f0.w);
      pk[4]=f2bf(f1.x); pk[5]=f2bf(f1.y); pk[6]=f2bf(f1.z); pk[7]=f2bf(f1.w);
      *(u16x8*)(Asb + m*40 + ks) = pk;
    }
    {   // stage B transposed: [n][k] bf16
      int k = tid >> 4, n8 = tid & 15;
      const float* src = B + (size_t)(k0 + k)*G3 + col0 + n8;
      #pragma unroll
      for (int i = 0; i < 8; ++i)
        Bsb[(n8 + 16*i)*40 + k] = f2bf(src[16*i]);
    }
    __syncthreads();
    const int mrow = wr*64, ncol = wc*32;
    const int fm = lane & 15, fk = (lane >> 4) * 8;
    bf16x8 bfr[2];
    #pragma unroll
    for (int j = 0; j < 2; ++j)
      bfr[j] = *(const bf16x8*)(Bsb + (ncol + j*16 + fm)*40 + fk);
    #pragma unroll
    for (int i = 0; i < 4; ++i){
      bf16x8 af = *(const bf16x8*)(Asb + (mrow + i*16 + fm)*40 + fk);
      acc[i][0] = __builtin_amdgcn_mfma_f32_16x16x32_bf16(af, bfr[0], acc[i][0], 0,0,0);
      acc[i][1] = __builtin_amdgcn_mfma_f32_16x16x32_bf16(af, bfr[1], acc[i][1], 0,0,0);
    }
    __syncthreads();
  }
  const int mrow = row0 + wr*64, ncol = col0 + wc*32;
  #pragma unroll
  for (int i = 0; i < 4; ++i)
    #pragma unroll
    for (int j = 0; j < 2; ++j){
      int cc = ncol + j*16 + (lane & 15);
      int rr = mrow + i*16 + (lane >> 4)*4;
      #pragma unroll
      for (int q = 0; q < 4; ++q)
        C[(size_t)(rr + q)*G3 + cc] = acc[i][j][q];
    }
}

// ---------------- persistent GRU scan --------------------------------------
// h_t:  hbuf [rep][t&1][1024]  {tag t   | 2x bf16}   (memset0 == h_0=0, tag 0)
// rh_t: rhbuf[rep][t&1][1024]  {tag t+1 | 2x bf16}
// Intra-block: wave-local pipelined slice poll -> deposit -> MFMA (no
// barrier); ONE __syncthreads per step; then ALL waves run the finalize
// redundantly (deterministic) and wave w stores replica w only — each
// consumer's replica goes out on the first store of its producer wave.
__global__ __launch_bounds__(512) void scan_kernel(
    const float* __restrict__ gates, const float* __restrict__ w_h,
    const float* __restrict__ b,
    u64* hbuf, u64* rhbuf, float* hfinal)
{
  __shared__ uint32_t vph[2][1024];    // packed h pairs
  __shared__ uint32_t vprh[2][1024];   // packed rh pairs (B only)
  __shared__ float    red0[32*9];      // A: r partials. B: z partials
  __shared__ float    red1[32*9];      // B: a partials
  __shared__ float    gx[2][64];       // x-gates (+bias): A uses 32, B 64
  __shared__ float    hloc[2][32];     // local f32 h state (B)
  __shared__ int      dead;
  volatile int* deadp = &dead;

  const int tid  = threadIdx.x;
  const int lane = tid & 63;
  const int wid  = tid >> 6;
  const bool isA = blockIdx.x < NA;
  const int  g   = isA ? (int)blockIdx.x : (int)blockIdx.x - NA;
  const int  rep = blockIdx.x & (NREP - 1);

  // Persistent weight fragments, k = wid*256 + s*32 + (lane>>4)*8 + j
  bf16x8 w0[8], w1[8], w2[8], w3[8];
  {
    const int kb0 = wid*256 + ((lane >> 4) << 3);
    const int c0  = isA ? (2048 + 32*g) : (32*g);     // A: r. B: z
    #pragma unroll
    for (int s = 0; s < 8; ++s){
      w0[s] = load_afrag(w_h, c0 + (lane & 15),      kb0 + s*32);
      w1[s] = load_afrag(w_h, c0 + 16 + (lane & 15), kb0 + s*32);
    }
    if (!isA){
      const int ca = 4096 + 32*g;
      #pragma unroll
      for (int s = 0; s < 8; ++s){
        w2[s] = load_afrag(w_h, ca + (lane & 15),      kb0 + s*32);
        w3[s] = load_afrag(w_h, ca + 16 + (lane & 15), kb0 + s*32);
      }
    }
  }

  if (tid == 0) *deadp = 0;
  if (tid < 64) ((float*)hloc)[tid] = 0.f;

  int   gcol = -1;
  float bias = 0.f;
  if (isA) { if (tid < 32) gcol = 2048 + 32*g + tid; }            // r gates
  else     { if (tid < 32)      gcol = 32*g + tid;                // z gates
             else if (tid < 64) gcol = 4096 + 32*g + (tid - 32);} // a gates
  if (gcol >= 0) { bias = b[gcol]; gx[0][tid] = gates[gcol] + bias; }
  __syncthreads();

  for (int t = 0; t < T_STEPS; ++t){
    const int par = t & 1;

    if (isA){
      // hop 1: pipelined wave-local h-slice poll; EVERY wave also grabs the
      // block's own 16 h u64s (needed for its redundant finalize).
      const u64* src = hbuf + ((size_t)(rep*2 + par))*HP;
      u64 vo = poll_slice<true>(src + wid*128, src + 16*g + lane, (uint32_t)t,
                                &vph[par][wid*128], lane, deadp);
      mv_pass(&vph[par][wid*128], w0, w1, red0, wid, lane);  // r pre-activations
      __syncthreads();
      if (*deadp) break;
      // all-wave redundant finalize; wave w publishes replica w
      uint32_t hp = __shfl((int)(uint32_t)vo, lane >> 1);
      if (lane < 32){
        float acc = 0.f;
        #pragma unroll
        for (int w = 0; w < 8; ++w) acc += red0[lane*9 + w];
        float pre = acc + gx[par][lane];
        float r = 1.f / (1.f + __expf(-pre));
        float hval = __uint_as_float((lane & 1) ? (hp & 0xffff0000u) : (hp << 16));
        float rh = r * hval;
        float other = __shfl_xor(rh, 1);
        if (!(lane & 1)){
          u64 pv = ((u64)(uint32_t)(t + 1) << 32)
                 | ((u64)f2bf(other) << 16) | (u64)f2bf(rh);
          astore(rhbuf + (size_t)(wid*2 + par)*HP + (size_t)((32*g + lane) >> 1), pv);
        }
        if (wid == 0){   // gates prefetch after publish; hides under next poll
          int tn = (t + 1 < T_STEPS) ? t + 1 : t;
          gx[par ^ 1][lane] = gates[(size_t)tn*G3 + gcol] + bias;
        }
      }
    } else {
      // hop 1: h slice (for z); z-mv overlaps A's r-compute
      const u64* hsrc = hbuf + ((size_t)(rep*2 + par))*HP;
      poll_slice<false>(hsrc + wid*128, (const u64*)0, (uint32_t)t,
                        &vph[par][wid*128], lane, deadp);
      mv_pass(&vph[par][wid*128], w0, w1, red0, wid, lane);  // z partials
      // hop 2: rh slice
      const u64* rsrc = rhbuf + ((size_t)(rep*2 + par))*HP;
      poll_slice<false>(rsrc + wid*128, (const u64*)0, (uint32_t)(t + 1),
                        &vprh[par][wid*128], lane, deadp);
      mv_pass(&vprh[par][wid*128], w2, w3, red1, wid, lane); // a partials
      __syncthreads();
      if (*deadp) break;
      // all-wave redundant finalize; wave w publishes replica w
      if (lane < 32){
        float zacc = 0.f, aacc = 0.f;
        #pragma unroll
        for (int w = 0; w < 8; ++w){ zacc += red0[lane*9 + w]; aacc += red1[lane*9 + w]; }
        float z = 1.f / (1.f + __expf(-(zacc + gx[par][lane])));
        float apre = aacc + gx[par][32 + lane];
        float e = __expf(2.f*apre);
        float a = 1.f - 2.f/(1.f + e);                  // tanh, saturation-safe
        float hold = hloc[par][lane];
        float hnew = hold + z*(a - hold);               // (1-z)h + z*a
        if (wid == 0) hloc[par ^ 1][lane] = hnew;
        float other = __shfl_xor(hnew, 1);
        if (!(lane & 1)){
          u64 pv = ((u64)(uint32_t)(t + 1) << 32)
                 | ((u64)f2bf(other) << 16) | (u64)f2bf(hnew);
          astore(hbuf + (size_t)(wid*2 + ((t+1)&1))*HP + (size_t)((32*g + lane) >> 1), pv);
        }
      }
      if (wid == 0 && gcol >= 0){        // prefetch z and a gate columns
        int tn = (t + 1 < T_STEPS) ? t + 1 : t;
        gx[par ^ 1][lane] = gates[(size_t)tn*G3 + gcol] + bias;
      }
    }
  }

  // T even -> final h in hloc[0]; kernel-boundary flush makes it visible
  if (!isA && tid < 32) hfinal[32*g + tid] = hloc[0][tid];
}

// ---------------- out = h_final @ w_out + b_out ----------------------------
__global__ __launch_bounds__(1024) void out_proj(const float* __restrict__ hfin,
                                                 const float* __restrict__ w_out,
                                                 const float* __restrict__ b_out,
                                                 float* __restrict__ out){
  __shared__ float red[16][80];
  const int g  = blockIdx.x;
  const int cl = threadIdx.x & 63;
  const int kc = threadIdx.x >> 6;        // 0..15
  const int col = 64*g + cl;
  float acc = 0.f;
  for (int k = kc*128; k < kc*128 + 128; ++k)
    acc = fmaf(hfin[k], w_out[(size_t)k*EOUT + col], acc);
  red[kc][cl] = acc;
  __syncthreads();
  if (kc == 0){
    float s = 0.f;
    #pragma unroll
    for (int q = 0; q < 16; ++q) s += red[q][cl];
    out[col] = s + b_out[col];
  }
}

extern "C" void kernel_launch(void* const* d_in, const int* in_sizes, int n_in,
                              void* d_out, int out_size, void* d_ws, size_t ws_size,
                              hipStream_t stream) {
  const float* x     = (const float*)d_in[0];   // (8192, 2048)
  const float* w_i   = (const float*)d_in[1];   // (2048, 6144)
  const float* w_h   = (const float*)d_in[2];   // (2048, 6144)
  const float* b     = (const float*)d_in[3];   // (6144,)
  const float* w_out = (const float*)d_in[4];   // (2048, 512)
  const float* b_out = (const float*)d_in[5];   // (512,)
  float* out = (float*)d_out;

  // Workspace: gates f32 (201.3MB) | hbuf u64[8][2][1024] | rhbuf u64[8][2][1024]
  //            | hfinal f32[2048]
  float* gates  = (float*)d_ws;
  u64*   hbuf   = (u64*)(gates + (size_t)T_STEPS * G3);
  u64*   rhbuf  = hbuf + (size_t)NREP*2*HP;
  float* hfinal = (float*)(rhbuf + (size_t)NREP*2*HP);
  (void)in_sizes; (void)n_in; (void)out_size; (void)ws_size;

  // zero tagged buffers: h_0=0 tag0 ready; rh never ready until written
  hipMemsetAsync(hbuf, 0, (size_t)(2*NREP*2*HP)*sizeof(u64), stream);

  gates_gemm<<<dim3((T_STEPS/128)*(G3/128)), dim3(512), 0, stream>>>(x, w_i, gates);

  const float* gates_c = gates;
  void* kargs[6];
  kargs[0] = (void*)&gates_c;
  kargs[1] = (void*)&w_h;
  kargs[2] = (void*)&b;
  kargs[3] = (void*)&hbuf;
  kargs[4] = (void*)&rhbuf;
  kargs[5] = (void*)&hfinal;
  hipLaunchCooperativeKernel((void*)scan_kernel, dim3(NA + NB), dim3(512), kargs, 0u, stream);

  out_proj<<<dim3(EOUT/64), dim3(1024), 0, stream>>>(hfinal, w_out, b_out, out);
}

// Round 13
// 27588.077 us; speedup vs baseline: 1.1150x; 1.1150x over previous
//
#include <hip/hip_runtime.h>
#include <stdint.h>

// Problem dims
#define T_STEPS 8192
#define DIN     2048
#define HD      2048
#define G3      6144
#define EOUT    512

// Scan partition: 64 A-blocks own 32 r-cols; 64 B-blocks own 32 z-cols +
// 32 a-cols + the h-update (z computed locally on B, off the critical path).
#define NA 64
#define NB 64
#define HP 1024          // h/rh broadcast: 1024 u64 pairs {tag | bf16 hi | bf16 lo}
#define NREP 8           // broadcast replicas
#define SPIN_MAX (1<<20)

typedef unsigned long long u64;
typedef __attribute__((ext_vector_type(8))) __bf16 bf16x8;
typedef __attribute__((ext_vector_type(8))) unsigned short u16x8;
typedef __attribute__((ext_vector_type(4))) float f32x4;

__device__ __forceinline__ uint16_t f2bf(float v){   // RNE f32->bf16
  uint32_t x = __float_as_uint(v);
  return (uint16_t)((x + 0x7fffu + ((x >> 16) & 1u)) >> 16);
}

__device__ __forceinline__ u64 aload(const u64* p){
  return __hip_atomic_load(p, __ATOMIC_RELAXED, __HIP_MEMORY_SCOPE_AGENT);
}
__device__ __forceinline__ void astore(u64* p, u64 v){
  __hip_atomic_store(p, v, __ATOMIC_RELAXED, __HIP_MEMORY_SCOPE_AGENT);
}

// A-fragment loader: lane supplies A[m = lane&15][k = kb + j], j=0..7,
// from w_h column `col` (f32, row-major, stride G3), converted to bf16.
__device__ __forceinline__ bf16x8 load_afrag(const float* __restrict__ w, int col, int kb){
  u16x8 r;
  #pragma unroll
  for (int j = 0; j < 8; ++j)
    r[j] = f2bf(w[(size_t)(kb + j)*G3 + col]);
  return __builtin_bit_cast(bf16x8, r);
}

// Wave-local tagged slice poll + LDS deposit. Each wave owns u64 elements
// [wid*128, wid*128+128) of the broadcast vector: lane takes the adjacent
// pair (2*lane, 2*lane+1) -> after tags are fresh, packs the two u32
// payloads into one ds_write_b64. If OWN=true, lanes 0..15 additionally
// poll u64 element (own_base + lane) and return it (A-finalize h values).
template<bool OWN>
__device__ __forceinline__ u64 poll_slice(const u64* src, uint32_t want,
                                          uint32_t* lds_slice, int own_base,
                                          int lane, volatile int* deadp){
  const u64* p0 = src + 2*lane;
  const u64* p1 = p0 + 1;
  const u64* po = src + own_base + lane;
  const bool need_own = OWN && (lane < 16);
  u64 v0, v1, vo = 0;
  int spins = 0;
  for(;;){
    v0 = aload(p0); v1 = aload(p1);
    if (need_own) vo = aload(po);
    bool ok = (uint32_t)(v0 >> 32) >= want && (uint32_t)(v1 >> 32) >= want &&
              (!need_own || (uint32_t)(vo >> 32) >= want);
    if (__all(ok)) break;
    if ((++spins & 63) == 0){
      if (*deadp) break;
      if (spins > SPIN_MAX){ *deadp = 1; break; }
    }
    __builtin_amdgcn_s_sleep(1);
  }
  u64 pk = ((u64)(uint32_t)v1 << 32) | (u64)(uint32_t)v0;
  *(u64*)&lds_slice[2*lane] = pk;         // wave-local; lgkmcnt orders vs reads
  return vo;
}

// One matvec pass over this wave's 256-elem k-slice: 16 MFMAs, two 16-col
// chains (wA, wB). Partials -> red[col*9 + wid]. Reads only the wave's own
// LDS slice (no cross-wave dependency -> no barrier needed before this).
__device__ __forceinline__ void mv_pass(const uint32_t* vp,
                                        const bf16x8* wA, const bf16x8* wB,
                                        float* red, int wid, int lane){
  const int boff = (lane >> 4) << 2;
  f32x4 acc0 = {0.f,0.f,0.f,0.f}, acc1 = {0.f,0.f,0.f,0.f};
  #pragma unroll
  for (int s = 0; s < 8; ++s){
    uint4 bu = *(const uint4*)(vp + s*16 + boff);
    bf16x8 bf = __builtin_bit_cast(bf16x8, bu);
    acc0 = __builtin_amdgcn_mfma_f32_16x16x32_bf16(wA[s], bf, acc0, 0, 0, 0);
    acc1 = __builtin_amdgcn_mfma_f32_16x16x32_bf16(wB[s], bf, acc1, 0, 0, 0);
  }
  if ((lane & 15) == 0){                  // D[:,0]: m = (lane>>4)*4 + r
    int mb = (lane >> 4) << 2;
    #pragma unroll
    for (int r = 0; r < 4; ++r){
      red[(mb + r)*9 + wid]      = acc0[r];
      red[(16 + mb + r)*9 + wid] = acc1[r];
    }
  }
}

// ------- gates GEMM (MFMA bf16): C[T,6144] = X[T,2048] @ Wi[2048,6144] -----
__global__ __launch_bounds__(512) void gates_gemm(const float* __restrict__ A,
                                                  const float* __restrict__ B,
                                                  float* __restrict__ C){
  __shared__ uint16_t Asb[128*40];
  __shared__ uint16_t Bsb[128*40];
  const int bm = blockIdx.x / (G3/128);
  const int bn = blockIdx.x % (G3/128);
  const int row0 = bm*128, col0 = bn*128;
  const int tid  = threadIdx.x;
  const int lane = tid & 63, wid = tid >> 6;
  const int wr = wid >> 2, wc = wid & 3;         // wave grid 2x4
  f32x4 acc[4][2] = {};
  for (int k0 = 0; k0 < DIN; k0 += 32){
    {   // stage A: [m][k] bf16
      int m = tid >> 2, ks = (tid & 3) * 8;
      const float* src = A + (size_t)(row0 + m)*DIN + k0 + ks;
      float4 f0 = *(const float4*)src;
      float4 f1 = *(const float4*)(src + 4);
      u16x8 pk;
      pk[0]=f2bf(f0.x); pk[1]=f2bf(f0.y); pk[2]=f2bf(f0.z); pk[3]=f2bf(f0.w);
      pk[4]=f2bf(f1.x); pk[5]=f2bf(f1.y); pk[6]=f2bf(f1.z); pk[7]=f2bf(f1.w);
      *(u16x8*)(Asb + m*40 + ks) = pk;
    }
    {   // stage B transposed: [n][k] bf16
      int k = tid >> 4, n8 = tid & 15;
      const float* src = B + (size_t)(k0 + k)*G3 + col0 + n8;
      #pragma unroll
      for (int i = 0; i < 8; ++i)
        Bsb[(n8 + 16*i)*40 + k] = f2bf(src[16*i]);
    }
    __syncthreads();
    const int mrow = wr*64, ncol = wc*32;
    const int fm = lane & 15, fk = (lane >> 4) * 8;
    bf16x8 bfr[2];
    #pragma unroll
    for (int j = 0; j < 2; ++j)
      bfr[j] = *(const bf16x8*)(Bsb + (ncol + j*16 + fm)*40 + fk);
    #pragma unroll
    for (int i = 0; i < 4; ++i){
      bf16x8 af = *(const bf16x8*)(Asb + (mrow + i*16 + fm)*40 + fk);
      acc[i][0] = __builtin_amdgcn_mfma_f32_16x16x32_bf16(af, bfr[0], acc[i][0], 0,0,0);
      acc[i][1] = __builtin_amdgcn_mfma_f32_16x16x32_bf16(af, bfr[1], acc[i][1], 0,0,0);
    }
    __syncthreads();
  }
  const int mrow = row0 + wr*64, ncol = col0 + wc*32;
  #pragma unroll
  for (int i = 0; i < 4; ++i)
    #pragma unroll
    for (int j = 0; j < 2; ++j){
      int cc = ncol + j*16 + (lane & 15);
      int rr = mrow + i*16 + (lane >> 4)*4;
      #pragma unroll
      for (int q = 0; q < 4; ++q)
        C[(size_t)(rr + q)*G3 + cc] = acc[i][j][q];
    }
}

// ---------------- persistent GRU scan --------------------------------------
// h_t:  hbuf [rep][t&1][1024]  {tag t   | 2x bf16}   (memset0 == h_0=0, tag 0)
// rh_t: rhbuf[rep][t&1][1024]  {tag t+1 | 2x bf16}
// Intra-block: wave-local slice poll -> deposit -> MFMA with NO barrier;
// exactly ONE __syncthreads per step (before the wave-0 finalize).
__global__ __launch_bounds__(512) void scan_kernel(
    const float* __restrict__ gates, const float* __restrict__ w_h,
    const float* __restrict__ b,
    u64* hbuf, u64* rhbuf, float* hfinal)
{
  __shared__ uint32_t vph[2][1024];    // packed h pairs
  __shared__ uint32_t vprh[2][1024];   // packed rh pairs (B only)
  __shared__ float    red0[32*9];      // A: r partials. B: z partials
  __shared__ float    red1[32*9];      // B: a partials
  __shared__ float    gx[2][64];       // x-gates (+bias): A uses 32, B 64
  __shared__ float    hloc[2][32];     // local f32 h state (B)
  __shared__ int      dead;
  volatile int* deadp = &dead;

  const int tid  = threadIdx.x;
  const int lane = tid & 63;
  const int wid  = tid >> 6;
  const bool isA = blockIdx.x < NA;
  const int  g   = isA ? (int)blockIdx.x : (int)blockIdx.x - NA;
  const int  rep = blockIdx.x & (NREP - 1);

  // Persistent weight fragments, k = wid*256 + s*32 + (lane>>4)*8 + j
  bf16x8 w0[8], w1[8], w2[8], w3[8];
  {
    const int kb0 = wid*256 + ((lane >> 4) << 3);
    const int c0  = isA ? (2048 + 32*g) : (32*g);     // A: r. B: z
    #pragma unroll
    for (int s = 0; s < 8; ++s){
      w0[s] = load_afrag(w_h, c0 + (lane & 15),      kb0 + s*32);
      w1[s] = load_afrag(w_h, c0 + 16 + (lane & 15), kb0 + s*32);
    }
    if (!isA){
      const int ca = 4096 + 32*g;
      #pragma unroll
      for (int s = 0; s < 8; ++s){
        w2[s] = load_afrag(w_h, ca + (lane & 15),      kb0 + s*32);
        w3[s] = load_afrag(w_h, ca + 16 + (lane & 15), kb0 + s*32);
      }
    }
  }

  if (tid == 0) *deadp = 0;
  if (tid < 64) ((float*)hloc)[tid] = 0.f;

  int   gcol = -1;
  float bias = 0.f;
  if (isA) { if (tid < 32) gcol = 2048 + 32*g + tid; }            // r gates
  else     { if (tid < 32)      gcol = 32*g + tid;                // z gates
             else if (tid < 64) gcol = 4096 + 32*g + (tid - 32);} // a gates
  if (gcol >= 0) { bias = b[gcol]; gx[0][tid] = gates[gcol] + bias; }
  __syncthreads();

  for (int t = 0; t < T_STEPS; ++t){
    const int par = t & 1;

    if (isA){
      // hop 1: wave-local h-slice poll+deposit; wave 0 also grabs own 16 h u64s
      const u64* src = hbuf + ((size_t)(rep*2 + par))*HP;
      u64 vo;
      if (wid == 0)
        vo = poll_slice<true >(src, (uint32_t)t, &vph[par][0],       16*g, lane, deadp);
      else
        vo = poll_slice<false>(src + wid*128, (uint32_t)t,
                               &vph[par][wid*128], 0, lane, deadp);
      mv_pass(&vph[par][wid*128], w0, w1, red0, wid, lane);  // r pre-activations
      __syncthreads();
      if (*deadp) break;
      if (wid == 0){
        // h values for rh: lane tid<32 needs payload of own-u64 (tid>>1), half (tid&1)
        uint32_t hp = __shfl((int)(uint32_t)vo, lane >> 1);
        if (lane < 32){
          float acc = 0.f;
          #pragma unroll
          for (int w = 0; w < 8; ++w) acc += red0[lane*9 + w];
          float pre = acc + gx[par][lane];
          float r = 1.f / (1.f + __expf(-pre));
          float hval = __uint_as_float((lane & 1) ? (hp & 0xffff0000u) : (hp << 16));
          float rh = r * hval;
          float other = __shfl_xor(rh, 1);
          if (!(lane & 1)){
            u64 pv = ((u64)(uint32_t)(t + 1) << 32)
                   | ((u64)f2bf(other) << 16) | (u64)f2bf(rh);
            size_t idx = (size_t)((32*g + lane) >> 1);
            #pragma unroll
            for (int rp = 0; rp < NREP; ++rp)
              astore(rhbuf + (size_t)(rp*2 + par)*HP + idx, pv);
          }
          // gates prefetch after publish: HBM latency hides under next poll
          int tn = (t + 1 < T_STEPS) ? t + 1 : t;
          gx[par ^ 1][lane] = gates[(size_t)tn*G3 + gcol] + bias;
        }
      }
    } else {
      // hop 1: h slice (for z); z-mv overlaps A's r-compute
      const u64* hsrc = hbuf + ((size_t)(rep*2 + par))*HP;
      poll_slice<false>(hsrc + wid*128, (uint32_t)t, &vph[par][wid*128], 0, lane, deadp);
      mv_pass(&vph[par][wid*128], w0, w1, red0, wid, lane);  // z partials
      // hop 2: rh slice
      const u64* rsrc = rhbuf + ((size_t)(rep*2 + par))*HP;
      poll_slice<false>(rsrc + wid*128, (uint32_t)(t + 1), &vprh[par][wid*128], 0, lane, deadp);
      mv_pass(&vprh[par][wid*128], w2, w3, red1, wid, lane); // a partials
      __syncthreads();
      if (*deadp) break;
      if (wid == 0 && lane < 32){
        float zacc = 0.f, aacc = 0.f;
        #pragma unroll
        for (int w = 0; w < 8; ++w){ zacc += red0[lane*9 + w]; aacc += red1[lane*9 + w]; }
        float z = 1.f / (1.f + __expf(-(zacc + gx[par][lane])));
        float apre = aacc + gx[par][32 + lane];
        float e = __expf(2.f*apre);
        float a = 1.f - 2.f/(1.f + e);                  // tanh, saturation-safe
        float hold = hloc[par][lane];
        float hnew = hold + z*(a - hold);               // (1-z)h + z*a
        hloc[par ^ 1][lane] = hnew;
        float other = __shfl_xor(hnew, 1);
        if (!(lane & 1)){
          u64 pv = ((u64)(uint32_t)(t + 1) << 32)
                 | ((u64)f2bf(other) << 16) | (u64)f2bf(hnew);
          size_t idx = (size_t)((32*g + lane) >> 1);
          #pragma unroll
          for (int rp = 0; rp < NREP; ++rp)
            astore(hbuf + (size_t)(rp*2 + ((t+1)&1))*HP + idx, pv);
        }
      }
      if (wid == 0 && gcol >= 0){        // prefetch z and a gate columns
        int tn = (t + 1 < T_STEPS) ? t + 1 : t;
        gx[par ^ 1][lane] = gates[(size_t)tn*G3 + gcol] + bias;
      }
    }
  }

  // T even -> final h in hloc[0]; kernel-boundary flush makes it visible
  if (!isA && tid < 32) hfinal[32*g + tid] = hloc[0][tid];
}

// ---------------- out = h_final @ w_out + b_out ----------------------------
__global__ __launch_bounds__(1024) void out_proj(const float* __restrict__ hfin,
                                                 const float* __restrict__ w_out,
                                                 const float* __restrict__ b_out,
                                                 float* __restrict__ out){
  __shared__ float red[16][80];
  const int g  = blockIdx.x;
  const int cl = threadIdx.x & 63;
  const int kc = threadIdx.x >> 6;        // 0..15
  const int col = 64*g + cl;
  float acc = 0.f;
  for (int k = kc*128; k < kc*128 + 128; ++k)
    acc = fmaf(hfin[k], w_out[(size_t)k*EOUT + col], acc);
  red[kc][cl] = acc;
  __syncthreads();
  if (kc == 0){
    float s = 0.f;
    #pragma unroll
    for (int q = 0; q < 16; ++q) s += red[q][cl];
    out[col] = s + b_out[col];
  }
}

extern "C" void kernel_launch(void* const* d_in, const int* in_sizes, int n_in,
                              void* d_out, int out_size, void* d_ws, size_t ws_size,
                              hipStream_t stream) {
  const float* x     = (const float*)d_in[0];   // (8192, 2048)
  const float* w_i   = (const float*)d_in[1];   // (2048, 6144)
  const float* w_h   = (const float*)d_in[2];   // (2048, 6144)
  const float* b     = (const float*)d_in[3];   // (6144,)
  const float* w_out = (const float*)d_in[4];   // (2048, 512)
  const float* b_out = (const float*)d_in[5];   // (512,)
  float* out = (float*)d_out;

  // Workspace: gates f32 (201.3MB) | hbuf u64[8][2][1024] | rhbuf u64[8][2][1024]
  //            | hfinal f32[2048]
  float* gates  = (float*)d_ws;
  u64*   hbuf   = (u64*)(gates + (size_t)T_STEPS * G3);
  u64*   rhbuf  = hbuf + (size_t)NREP*2*HP;
  float* hfinal = (float*)(rhbuf + (size_t)NREP*2*HP);
  (void)in_sizes; (void)n_in; (void)out_size; (void)ws_size;

  // zero tagged buffers: h_0=0 tag0 ready; rh never ready until written
  hipMemsetAsync(hbuf, 0, (size_t)(2*NREP*2*HP)*sizeof(u64), stream);

  gates_gemm<<<dim3((T_STEPS/128)*(G3/128)), dim3(512), 0, stream>>>(x, w_i, gates);

  const float* gates_c = gates;
  void* kargs[6];
  kargs[0] = (void*)&gates_c;
  kargs[1] = (void*)&w_h;
  kargs[2] = (void*)&b;
  kargs[3] = (void*)&hbuf;
  kargs[4] = (void*)&rhbuf;
  kargs[5] = (void*)&hfinal;
  hipLaunchCooperativeKernel((void*)scan_kernel, dim3(NA + NB), dim3(512), kargs, 0u, stream);

  out_proj<<<dim3(EOUT/64), dim3(1024), 0, stream>>>(hfinal, w_out, b_out, out);
}